// Round 7
// baseline (200.320 us; speedup 1.0000x reference)
//
#include <hip/hip_runtime.h>
#include <math.h>

// Problem constants (fixed by the reference):
// B=2, N=131072 (=2^17), K=9, P=4, D=4, S=1, CI=8, CO=8
#define N_PTS 131072
#define KNB   9
#define PD    16
#define CIN   8
#define COUT  8
#define THREADS 256       // one point per thread; 4 waves/block
#define WAVES   4
#define POOLF   1728      // floats per wave pool: 576 ddx | 576 ddy | 576 adj(int)

// Native clang vectors (required by nontemporal builtins; map to packed fp32 math).
typedef float f32x2 __attribute__((ext_vector_type(2)));
typedef float f32x4 __attribute__((ext_vector_type(4)));
typedef int   i32x4 __attribute__((ext_vector_type(4)));

#if __has_builtin(__builtin_amdgcn_exp2f)
#define EXP2F(v) __builtin_amdgcn_exp2f(v)
#else
#define EXP2F(v) exp2f(v)
#endif

__global__ __launch_bounds__(THREADS) void polnormal_kernel(
    const float* __restrict__ x,      // (B, N, CI)
    const float* __restrict__ dx,     // (B, N, K)
    const float* __restrict__ dy,     // (B, N, K)
    const int*   __restrict__ adj,    // (N, K)
    const float* __restrict__ phis,  // (P,)
    const float* __restrict__ dists, // (D,)
    const float* __restrict__ sigma, // (S,) = (1,)
    const float* __restrict__ amp,   // (P, D, S, CI, CO) = (pd, c, o)
    float*       __restrict__ out)   // (B, N, P, D, S, CO)
{
    // Per-wave pool: staging for ddx/ddy/adj of the wave's 64 points; after
    // consumption into registers the SAME region becomes the wave-private
    // output-transpose buffer (64 pts * 20 floats = 1280 < 1728).
    // NOTE: no s_amp — amp is read via wave-uniform addresses directly from
    // global, which selects to s_load (scalar cache). R6 spent ~48 cyc/pt of
    // LDS pipe re-reading 4 KB of amp per point; that was the top consumer.
    __shared__ float s_pool[WAVES * POOLF];     // 27648 B
    __shared__ f32x2 s_t12[PD];                 // (-2*c1*mux, -2*c1*muy)
    __shared__ float s_rr[PD];                  // c1*(mux^2+muy^2)
    __shared__ float s_c[2];                    // c1, c2

    const int  tid    = threadIdx.x;
    const long base_g = (long)blockIdx.x * THREADS;   // flattened (b,n); 256 | N
    const int  b      = (int)(base_g >> 17);          // N = 2^17
    const int  base_n = (int)(base_g & (N_PTS - 1));

    // --- Staging (single barrier) ---
    // dx/dy/adj are stream-once -> NONTEMPORAL (keep L2 for the reused x).
    for (int t = tid; t < 576; t += THREADS) {
        f32x4 vx = __builtin_nontemporal_load(&((const f32x4*)dx)[(long)blockIdx.x * 576 + t]);
        f32x4 vy = __builtin_nontemporal_load(&((const f32x4*)dy)[(long)blockIdx.x * 576 + t]);
        i32x4 va = __builtin_nontemporal_load(&((const i32x4*)adj)[((long)base_n * KNB) / 4 + t]);
        const int w   = (4 * t) / 576;       // 4|576 -> all 4 elems same wave pool
        const int idx = (4 * t) % 576;
        *(f32x4*)&s_pool[w * POOLF + idx]        = vx;
        *(f32x4*)&s_pool[w * POOLF + 576 + idx]  = vy;
        *(i32x4*)&s_pool[w * POOLF + 1152 + idx] = va;
    }

    // Per-pd constants, computed once per block.
    if (tid < PD) {
        const float sig = fmaxf(sigma[0], 1e-10f);
        const float s2  = sig * sig;
        const float c1  = (-0.5f / s2) * 1.44269504088896340736f;  // log2 e
        const int p = tid >> 2, d = tid & 3;
        float sn, cs;
        __sincosf(phis[p], &sn, &cs);
        const float dist = dists[d];
        const float mux = cs * dist, muy = sn * dist;
        s_t12[tid] = (f32x2){ -2.0f * c1 * mux, -2.0f * c1 * muy };
        s_rr[tid]  = c1 * (mux * mux + muy * muy);
        if (tid == 0) {
            s_c[0] = c1;
            s_c[1] = -0.5f * __log2f(6.283185307179586f * s2);   // log2(norm)
        }
    }
    __syncthreads();

    // --- Compute: this thread owns point (b, base_n + tid) ---
    const int w = tid >> 6;          // wave id
    const int l = tid & 63;          // lane
    float* poolw = &s_pool[w * POOLF];

    // dd + adj into registers (conflict-free b32: lane stride 9 words, odd).
    float ddxv[KNB], ddyv[KNB];
    int   rows[KNB];
#pragma unroll
    for (int k = 0; k < KNB; ++k) {
        ddxv[k] = poolw[l * KNB + k];
        ddyv[k] = poolw[576 + l * KNB + k];
        rows[k] = ((const int*)poolw)[1152 + l * KNB + k];
    }

    // Gather x rows into registers (18 independent loads; x stays L2-resident
    // because every streaming access in this kernel is nontemporal).
    f32x4 xr[KNB][2];
#pragma unroll
    for (int k = 0; k < KNB; ++k) {
        const f32x4* src = (const f32x4*)(x + (((long)b << 17) + rows[k]) * CIN);
        xr[k][0] = src[0];
        xr[k][1] = src[1];
    }

    // A[k] = c1*(ddx^2+ddy^2) + c2 (pd-independent exponent part);
    // full arg = A[k] + rr[pd] + t1[pd]*ddx + t2[pd]*ddy.
    const float c1 = s_c[0], c2 = s_c[1];
    float Ak[KNB];
#pragma unroll
    for (int k = 0; k < KNB; ++k) {
        const float q = fmaf(ddxv[k], ddxv[k], ddyv[k] * ddyv[k]);
        Ak[k] = fmaf(q, c1, c2);
    }

    // Output in 8 chunks of 2 pd cells, transposed through wave-private LDS so
    // every global store instruction writes full 64B sectors back-to-back.
    float* bufw = poolw;             // reuse: 64 pts * 20 floats (80B stride)
    const int pt_l = l >> 2;         // store phase: 4 lanes per point
    const int u    = l & 3;

    for (int c = 0; c < 8; ++c) {
        f32x4 accq[4];               // 2 pd * (2 quads of 4 outputs)
#pragma unroll
        for (int h = 0; h < 2; ++h) {
            const int pdc = 2 * c + h;
            const f32x2 t12 = s_t12[pdc];      // wave-uniform broadcast
            const float rr  = s_rr[pdc];

            f32x4 wx0 = (f32x4)(0.0f), wx1 = (f32x4)(0.0f);
#pragma unroll
            for (int k = 0; k < KNB; ++k) {
                const float arg = fmaf(t12.x, ddxv[k], fmaf(t12.y, ddyv[k], Ak[k] + rr));
                const float wgt = EXP2F(arg);
                const f32x4 wv  = (f32x4)(wgt);
                wx0 += wv * xr[k][0];          // packed fma
                wx1 += wv * xr[k][1];
            }

            // Matvec. amp addresses are WAVE-UNIFORM (depend only on pdc/cc)
            // -> compiler selects s_load through the scalar cache: zero LDS
            // traffic, VALU sees one SGPR operand per fma.
            const float* __restrict__ arow = amp + pdc * (CIN * COUT);
            f32x4 acc0 = (f32x4)(0.0f), acc1 = (f32x4)(0.0f);
#pragma unroll
            for (int cc = 0; cc < CIN; ++cc) {
                const float wc  = (cc < 4) ? wx0[cc] : wx1[cc - 4];
                const f32x4 wcv = (f32x4)(wc);
                acc0 += wcv * *(const f32x4*)(arow + cc * 8);
                acc1 += wcv * *(const f32x4*)(arow + cc * 8 + 4);
            }
            accq[2 * h]     = acc0;
            accq[2 * h + 1] = acc1;
        }

        // Wave-private transpose. lgkmcnt(0) fences: (a) prior chunk's buf
        // reads done before overwrite, (b) writes visible before readback.
        // Quad index XOR-swizzled by (pt>>3)&3: un-swizzled, lanes {0,8,16,..}
        // share a bank quad (8-way conflict, ~2.9x); swizzled, max 2-way (free).
        asm volatile("s_waitcnt lgkmcnt(0)" ::: "memory");
#pragma unroll
        for (int q = 0; q < 4; ++q)
            *(f32x4*)&bufw[l * 20 + (q ^ ((l >> 3) & 3)) * 4] = accq[q];
        asm volatile("s_waitcnt lgkmcnt(0)" ::: "memory");
        __builtin_amdgcn_sched_barrier(0);

        // Coalesced NT stores: lane (pt_l,u), 4 groups -> 64 pts * 64 B chunk.
#pragma unroll
        for (int g = 0; g < 4; ++g) {
            const int pt = pt_l + 16 * g;
            const f32x4 v = *(const f32x4*)&bufw[pt * 20 + (u ^ ((pt >> 3) & 3)) * 4];
            float* dst = out + ((long)(base_g + w * 64 + pt)) * (PD * COUT) + c * 16 + u * 4;
            __builtin_nontemporal_store(v, (f32x4*)dst);
        }
    }
}

extern "C" void kernel_launch(void* const* d_in, const int* in_sizes, int n_in,
                              void* d_out, int out_size, void* d_ws, size_t ws_size,
                              hipStream_t stream) {
    const float* x     = (const float*)d_in[0];
    const float* dx    = (const float*)d_in[1];
    const float* dy    = (const float*)d_in[2];
    const int*   adj   = (const int*)  d_in[3];
    const float* phis  = (const float*)d_in[4];
    const float* dists = (const float*)d_in[5];
    const float* sigma = (const float*)d_in[6];
    const float* amp   = (const float*)d_in[7];
    float* out = (float*)d_out;

    const int total_pts = 2 * N_PTS;                 // B*N = 262144
    const int grid = total_pts / THREADS;            // 1024 blocks
    polnormal_kernel<<<grid, THREADS, 0, stream>>>(x, dx, dy, adj, phis, dists,
                                                   sigma, amp, out);
}

// Round 8
// 191.542 us; speedup vs baseline: 1.0458x; 1.0458x over previous
//
#include <hip/hip_runtime.h>
#include <math.h>

// Problem constants (fixed by the reference):
// B=2, N=131072 (=2^17), K=9, P=4, D=4, S=1, CI=8, CO=8
#define N_PTS 131072
#define KNB   9
#define PD    16
#define CIN   8
#define COUT  8
#define THREADS 256       // one point per thread; 4 waves/block
#define WAVES   4
#define POOLF   2064      // floats/wave pool: staging (1728) then transpose buf (2048)

// Native clang vectors (required by nontemporal builtins; map to packed fp32 math).
typedef float f32x2 __attribute__((ext_vector_type(2)));
typedef float f32x4 __attribute__((ext_vector_type(4)));
typedef int   i32x4 __attribute__((ext_vector_type(4)));

#if __has_builtin(__builtin_amdgcn_exp2f)
#define EXP2F(v) __builtin_amdgcn_exp2f(v)
#else
#define EXP2F(v) exp2f(v)
#endif

__global__ __launch_bounds__(THREADS) void polnormal_kernel(
    const float* __restrict__ x,      // (B, N, CI)
    const float* __restrict__ dx,     // (B, N, K)
    const float* __restrict__ dy,     // (B, N, K)
    const int*   __restrict__ adj,    // (N, K)
    const float* __restrict__ phis,  // (P,)
    const float* __restrict__ dists, // (D,)
    const float* __restrict__ sigma, // (S,) = (1,)
    const float* __restrict__ amp,   // (P, D, S, CI, CO) = (pd, c, o)
    float*       __restrict__ out)   // (B, N, P, D, S, CO)
{
    // Per-wave pool: staging for ddx/ddy/adj (1728 floats), then reused as the
    // wave-private output-transpose buffer (64 pts * 32 floats = 2048 floats).
    // Wave-private reuse => no __syncthreads after the initial one.
    __shared__ float s_pool[WAVES * POOLF];     // 33 KB
    __shared__ f32x2 s_t12[PD];                 // (-2*c1*mux, -2*c1*muy)
    __shared__ float s_rr[PD];                  // c1*(mux^2+muy^2)
    __shared__ float s_c[2];                    // c1, c2

    const int  tid    = threadIdx.x;
    const long base_g = (long)blockIdx.x * THREADS;   // flattened (b,n); 256 | N
    const int  b      = (int)(base_g >> 17);          // N = 2^17
    const int  base_n = (int)(base_g & (N_PTS - 1));

    // --- Staging (single barrier) ---
    // dx/dy/adj are stream-once -> NONTEMPORAL (keep L2 for the reused x).
    for (int t = tid; t < 576; t += THREADS) {
        f32x4 vx = __builtin_nontemporal_load(&((const f32x4*)dx)[(long)blockIdx.x * 576 + t]);
        f32x4 vy = __builtin_nontemporal_load(&((const f32x4*)dy)[(long)blockIdx.x * 576 + t]);
        i32x4 va = __builtin_nontemporal_load(&((const i32x4*)adj)[((long)base_n * KNB) / 4 + t]);
        const int w   = (4 * t) / 576;       // 4|576 -> all 4 elems same wave pool
        const int idx = (4 * t) % 576;
        *(f32x4*)&s_pool[w * POOLF + idx]        = vx;
        *(f32x4*)&s_pool[w * POOLF + 576 + idx]  = vy;
        *(i32x4*)&s_pool[w * POOLF + 1152 + idx] = va;
    }

    // Per-pd constants, computed once per block.
    if (tid < PD) {
        const float sig = fmaxf(sigma[0], 1e-10f);
        const float s2  = sig * sig;
        const float c1  = (-0.5f / s2) * 1.44269504088896340736f;  // log2 e
        const int p = tid >> 2, d = tid & 3;
        float sn, cs;
        __sincosf(phis[p], &sn, &cs);
        const float dist = dists[d];
        const float mux = cs * dist, muy = sn * dist;
        s_t12[tid] = (f32x2){ -2.0f * c1 * mux, -2.0f * c1 * muy };
        s_rr[tid]  = c1 * (mux * mux + muy * muy);
        if (tid == 0) {
            s_c[0] = c1;
            s_c[1] = -0.5f * __log2f(6.283185307179586f * s2);   // log2(norm)
        }
    }
    __syncthreads();

    // --- Compute: this thread owns point (b, base_n + tid) ---
    const int w = tid >> 6;          // wave id
    const int l = tid & 63;          // lane
    float* poolw = &s_pool[w * POOLF];

    // dd + adj into registers (conflict-free b32: lane stride 9 words, odd).
    float ddxv[KNB], ddyv[KNB];
    int   rows[KNB];
#pragma unroll
    for (int k = 0; k < KNB; ++k) {
        ddxv[k] = poolw[l * KNB + k];
        ddyv[k] = poolw[576 + l * KNB + k];
        rows[k] = ((const int*)poolw)[1152 + l * KNB + k];
    }

    // Gather x rows into registers (18 independent loads; x stays L2-resident
    // because every streaming access in this kernel is nontemporal).
    f32x4 xr[KNB][2];
#pragma unroll
    for (int k = 0; k < KNB; ++k) {
        const f32x4* src = (const f32x4*)(x + (((long)b << 17) + rows[k]) * CIN);
        xr[k][0] = src[0];
        xr[k][1] = src[1];
    }

    // A[k] = c1*(ddx^2+ddy^2) + c2 (pd-independent exponent part);
    // full arg = A[k] + rr[pd] + t1[pd]*ddx + t2[pd]*ddy.
    const float c1 = s_c[0], c2 = s_c[1];
    float Ak[KNB];
#pragma unroll
    for (int k = 0; k < KNB; ++k) {
        const float q = fmaf(ddxv[k], ddxv[k], ddyv[k] * ddyv[k]);
        Ak[k] = fmaf(q, c1, c2);
    }

    // Output in 4 chunks of 4 pd cells. Each point's chunk is a CONTIGUOUS
    // 128 B run (R6/R7 emitted 64 B runs at 512 B stride -> half of each 128 B
    // TCC line dirtied per NT store -> write amplification; that invariant
    // explains the ~2.8 TB/s effective-BW ceiling across all prior variants).
    float* bufw = poolw;             // reuse: 64 pts * 32 floats (128 B/pt)
    const int pt8 = l >> 3;          // store phase: 8 lanes per point
    const int u8  = l & 7;

    for (int c4 = 0; c4 < 4; ++c4) {
        f32x4 accq[8];               // 4 pd * 2 quads = this chunk's 32 floats
#pragma unroll
        for (int h = 0; h < 4; ++h) {
            const int pdc = 4 * c4 + h;
            const f32x2 t12 = s_t12[pdc];      // wave-uniform broadcast
            const float rr  = s_rr[pdc];

            f32x4 wx0 = (f32x4)(0.0f), wx1 = (f32x4)(0.0f);
#pragma unroll
            for (int k = 0; k < KNB; ++k) {
                const float arg = fmaf(t12.x, ddxv[k], fmaf(t12.y, ddyv[k], Ak[k] + rr));
                const float wgt = EXP2F(arg);
                const f32x4 wv  = (f32x4)(wgt);
                wx0 += wv * xr[k][0];          // packed fma
                wx1 += wv * xr[k][1];
            }

            // Matvec. amp addresses are WAVE-UNIFORM -> scalar loads (K$),
            // zero LDS traffic.
            const float* __restrict__ arow = amp + pdc * (CIN * COUT);
            f32x4 acc0 = (f32x4)(0.0f), acc1 = (f32x4)(0.0f);
#pragma unroll
            for (int cc = 0; cc < CIN; ++cc) {
                const float wc  = (cc < 4) ? wx0[cc] : wx1[cc - 4];
                const f32x4 wcv = (f32x4)(wc);
                acc0 += wcv * *(const f32x4*)(arow + cc * 8);
                acc1 += wcv * *(const f32x4*)(arow + cc * 8 + 4);
            }
            accq[2 * h]     = acc0;
            accq[2 * h + 1] = acc1;
        }

        // Wave-private transpose. lgkmcnt(0) fences: (a) prior chunk's buf
        // reads done before overwrite, (b) writes visible before readback.
        // Granule mapping l*8 + (q ^ (l&7)) is a latin square in (bank-quad,
        // lane) -> both write and read sides spread evenly over all 8
        // 16B-bank-quads (no conflict beyond the wave64 minimum).
        asm volatile("s_waitcnt lgkmcnt(0)" ::: "memory");
#pragma unroll
        for (int q = 0; q < 8; ++q)
            *(f32x4*)&bufw[(l * 8 + (q ^ (l & 7))) * 4] = accq[q];
        asm volatile("s_waitcnt lgkmcnt(0)" ::: "memory");
        __builtin_amdgcn_sched_barrier(0);

        // Coalesced NT stores: 8 lanes cover one point's 128 B run; one
        // wave-store = 8 points * 128 B FULL lines. 8 groups -> 64 points.
#pragma unroll
        for (int g = 0; g < 8; ++g) {
            const int pt = pt8 + 8 * g;
            const f32x4 v = *(const f32x4*)&bufw[(pt * 8 + (u8 ^ (pt & 7))) * 4];
            float* dst = out + (long)(base_g + w * 64 + pt) * (PD * COUT) + c4 * 32 + u8 * 4;
            __builtin_nontemporal_store(v, (f32x4*)dst);
        }
    }
}

extern "C" void kernel_launch(void* const* d_in, const int* in_sizes, int n_in,
                              void* d_out, int out_size, void* d_ws, size_t ws_size,
                              hipStream_t stream) {
    const float* x     = (const float*)d_in[0];
    const float* dx    = (const float*)d_in[1];
    const float* dy    = (const float*)d_in[2];
    const int*   adj   = (const int*)  d_in[3];
    const float* phis  = (const float*)d_in[4];
    const float* dists = (const float*)d_in[5];
    const float* sigma = (const float*)d_in[6];
    const float* amp   = (const float*)d_in[7];
    float* out = (float*)d_out;

    const int total_pts = 2 * N_PTS;                 // B*N = 262144
    const int grid = total_pts / THREADS;            // 1024 blocks
    polnormal_kernel<<<grid, THREADS, 0, stream>>>(x, dx, dy, adj, phis, dists,
                                                   sigma, amp, out);
}